// Round 19
// baseline (225.102 us; speedup 1.0000x reference)
//
#include <hip/hip_runtime.h>
#include <math.h>

#define HH 256
#define WW 256
#define HW (HH*WW)
#define NPX (2*HW)          // 131072 pixels total

typedef __attribute__((ext_vector_type(8))) short bf16x8;
typedef __attribute__((ext_vector_type(4))) float f32x4;
typedef __attribute__((ext_vector_type(2))) float f32x2;

__device__ __forceinline__ float bf2f(short h) {
    union { unsigned u; float f; } v; v.u = ((unsigned)(unsigned short)h) << 16; return v.f;
}
__device__ __forceinline__ short f2bf(float f) {        // RNE
    union { float f; unsigned u; } v; v.f = f;
    unsigned r = v.u + 0x7fffu + ((v.u >> 16) & 1u);
    return (short)(r >> 16);
}
__device__ __forceinline__ float uasf(unsigned u) {
    union { unsigned u; float f; } v; v.u = u; return v.f;
}
__device__ __forceinline__ unsigned fasu(float f) {
    union { float f; unsigned u; } v; v.f = f; return v.u;
}
// unpack dword holding 2 bf16 (lo=elem0, hi=elem1) -> f32x2
__device__ __forceinline__ f32x2 bfpair(unsigned u) {
    f32x2 r; r[0] = uasf(u << 16); r[1] = uasf(u & 0xffff0000u); return r;
}

// ---------- x NCHW fp32 -> channel-last bf16 + (blocks 0..143) weight prep ----------
// wt3 layout: [kb=k/8][n][j=k%8]  (k = t*64+c)
__global__ __launch_bounds__(256) void k_x2cl(const float* __restrict__ x,
        short* __restrict__ xcl,
        const float* __restrict__ w_om, const float* __restrict__ w_dcn,
        const float* __restrict__ w_h,  const float* __restrict__ w_w,
        const float* __restrict__ w3,
        short* __restrict__ wt_om, short* __restrict__ wt_dcn,
        short* __restrict__ wt_h,  short* __restrict__ wt_w,
        float* __restrict__ w3t) {
    __shared__ short tile[256 * 66];
    const int xx = threadIdx.x;
    const int row = blockIdx.x;               // b*256 + y
    const int b = row >> 8, y = row & 255;
    for (int c = 0; c < 64; ++c)
        tile[xx * 66 + c] = f2bf(x[((b * 64 + c) << 16) + (y << 8) + xx]);
    int i = blockIdx.x * 256 + threadIdx.x;
    if (i < 64 * 576) {
        int o = i / 576, k = i - o * 576, t = k >> 6, c = k & 63;
        int kb = k >> 3, j = k & 7;
        int src = (o * 64 + c) * 9 + t;
        int dst = (kb * 64 + o) * 8 + j;
        wt_dcn[dst] = f2bf(w_dcn[src]);
        wt_h[dst]   = f2bf(w_h[src]);
        wt_w[dst]   = f2bf(w_w[src]);
        if (o < 32) wt_om[(kb * 32 + o) * 8 + j] = (o < 27) ? f2bf(w_om[src]) : (short)0;
        if (o == 0) w3t[k] = w3[c * 9 + t];
    }
    __syncthreads();
    short* op = xcl + ((row << 8) + xx) * 64;
#pragma unroll
    for (int j = 0; j < 8; ++j) {
        bf16x8 v;
#pragma unroll
        for (int e = 0; e < 8; ++e) v[e] = tile[xx * 66 + j * 8 + e];
        *(bf16x8*)(op + j * 8) = v;
    }
}

#define XPS 72   // LDS pixel stride (shorts): 144B, 16B-aligned

// ---------- FUSED om-conv + modulated deformable conv + BN1 + ReLU ----------
// R19: grid split into 2x1024-block dispatches (blk0 offset) so the other
// kernels surface in the profiler's top-5. Body identical to R18.
__global__ __launch_bounds__(256) __attribute__((amdgpu_waves_per_eu(2, 4)))
void k_dcn_mfma(const short* __restrict__ xcl,
        const short* __restrict__ wom, const float* __restrict__ b_om,
        const short* __restrict__ wt,
        const float* __restrict__ bias,
        const float* __restrict__ gg, const float* __restrict__ be,
        const float* __restrict__ mu, const float* __restrict__ var,
        short* __restrict__ out_cl, int blk0) {
    __shared__ short xt[256 * XPS];                 // 36,864 B
    __shared__ _Float16 om_lds[64 * 28];            //  3,584 B
    const int lane = threadIdx.x & 63, wave = threadIdx.x >> 6;
    const int quad = lane >> 4, l16 = lane & 15;
    const int bid = blockIdx.x + blk0;
    const int band = bid & 7, idx = bid >> 3;
    const int tr = band * 8 + (idx >> 5), tc = idx & 31;
    const int b = tr >> 5;
    const int ty0 = (tr & 31) * 8, tx0 = tc * 8;
    const int base = b << 16;
    const int hy0 = ty0 - 4, hx0 = tx0 - 4;
    // ---- stage 16x16 halo (clamped) ----
    {
        const int p = threadIdx.x;
        const int sy = min(max(hy0 + (p >> 4), 0), 255);
        const int sx = min(max(hx0 + (p & 15), 0), 255);
        const short* src = xcl + (size_t)((base + sy * 256 + sx) * 64);
        short* dst = &xt[p * XPS];
#pragma unroll
        for (int j = 0; j < 8; ++j)
            *(bf16x8*)(dst + j * 8) = *(const bf16x8*)(src + j * 8);
    }
    __syncthreads();

    const int lp = wave * 16 + l16;        // tile-local pixel (A-row m=l16)
    const int pyy = lp >> 3, pxx = lp & 7;
    const int y = ty0 + pyy, x = tx0 + pxx;

    // ---- phase 1: om conv for this tile (zero-OOB taps) ----
    {
        f32x4 oacc[2];
        oacc[0] = (f32x4){0,0,0,0}; oacc[1] = (f32x4){0,0,0,0};
        auto loadOB = [&](int s, bf16x8* Bv) {
            const int kb = s * 4 + quad;
#pragma unroll
            for (int g = 0; g < 2; ++g)
                Bv[g] = *(const bf16x8*)(wom + (kb * 32 + g * 16 + l16) * 8);
        };
        bf16x8 OB[2][2];
        loadOB(0, OB[0]);
#pragma unroll
        for (int s = 0; s < 18; ++s) {
            if (s < 17) loadOB(s + 1, OB[(s + 1) & 1]);
            const int t = s >> 1, c0 = (s & 1) * 32;
            const int dy = t / 3 - 1, dx = t % 3 - 1;
            bf16x8 av = *(const bf16x8*)&xt[((pyy + 4 + dy) * 16 + (pxx + 4 + dx)) * XPS + c0 + quad * 8];
            bool ok = ((unsigned)(y + dy) < 256u) && ((unsigned)(x + dx) < 256u);
            if (!ok) { bf16x8 z = {0,0,0,0,0,0,0,0}; av = z; }
#pragma unroll
            for (int g = 0; g < 2; ++g)
                oacc[g] = __builtin_amdgcn_mfma_f32_16x16x32_bf16(av, OB[s & 1][g], oacc[g], 0, 0, 0);
        }
#pragma unroll
        for (int g = 0; g < 2; ++g) {
            int o = g * 16 + l16;
            if (o < 27) {
                float bo = b_om[o];
#pragma unroll
                for (int r = 0; r < 4; ++r) {
                    float v = oacc[g][r] + bo;
                    if (o >= 18) v = 1.f / (1.f + expf(-v));     // sigmoid(mask)
                    om_lds[(wave * 16 + quad * 4 + r) * 28 + o] = (_Float16)v;
                }
            }
        }
    }
    __syncthreads();

    // ---- phase 2: deformable conv ----
    f32x4 acc[4];
#pragma unroll
    for (int i = 0; i < 4; ++i) acc[i] = (f32x4){0,0,0,0};

    float omr[27];
#pragma unroll
    for (int j = 0; j < 27; ++j) omr[j] = (float)om_lds[lp * 28 + j];

#pragma unroll
    for (int t = 0; t < 9; ++t) {
        const int ky = t / 3 - 1, kx = t % 3 - 1;
        float o1 = omr[t], o2 = omr[9 + t], m = omr[18 + t];
        float py = (float)(y + ky) + o1;
        float px = (float)(x + kx) + o2;
        float y0f = floorf(py), x0f = floorf(px);
        float wy1 = py - y0f, wx1 = px - x0f;
        int y0 = (int)y0f, xi0 = (int)x0f, y1 = y0 + 1, xi1 = xi0 + 1;
        float w00 = (1.f - wy1) * (1.f - wx1) * m;
        float w01 = (1.f - wy1) * wx1 * m;
        float w10 = wy1 * (1.f - wx1) * m;
        float w11 = wy1 * wx1 * m;
        if (!((unsigned)y0  < 256u)) { w00 = 0.f; w01 = 0.f; }
        if (!((unsigned)y1  < 256u)) { w10 = 0.f; w11 = 0.f; }
        if (!((unsigned)xi0 < 256u)) { w00 = 0.f; w10 = 0.f; }
        if (!((unsigned)xi1 < 256u)) { w01 = 0.f; w11 = 0.f; }
        int cy0 = min(max(y0, 0), 255), cy1 = min(max(y1, 0), 255);
        int cx0 = min(max(xi0, 0), 255), cx1 = min(max(xi1, 0), 255);
        int iy0 = cy0 - hy0, iy1 = cy1 - hy0;
        int ix0 = cx0 - hx0, ix1 = cx1 - hx0;
        bool inh = ((unsigned)iy0 < 16u) && ((unsigned)iy1 < 16u)
                && ((unsigned)ix0 < 16u) && ((unsigned)ix1 < 16u);

        bf16x8 C[2][4];
        if (__all(inh)) {
            const int p00 = (iy0 * 16 + ix0) * XPS, p01 = (iy0 * 16 + ix1) * XPS;
            const int p10 = (iy1 * 16 + ix0) * XPS, p11 = (iy1 * 16 + ix1) * XPS;
#pragma unroll
            for (int h = 0; h < 2; ++h) {
                const int cb = h * 32 + quad * 8;
                C[h][0] = *(const bf16x8*)&xt[p00 + cb];
                C[h][1] = *(const bf16x8*)&xt[p01 + cb];
                C[h][2] = *(const bf16x8*)&xt[p10 + cb];
                C[h][3] = *(const bf16x8*)&xt[p11 + cb];
            }
        } else {
            const int i00 = (base + cy0 * 256 + cx0) * 64;
            const int i01 = (base + cy0 * 256 + cx1) * 64;
            const int i10 = (base + cy1 * 256 + cx0) * 64;
            const int i11 = (base + cy1 * 256 + cx1) * 64;
#pragma unroll
            for (int h = 0; h < 2; ++h) {
                const int cb = h * 32 + quad * 8;
                C[h][0] = *(const bf16x8*)(xcl + i00 + cb);
                C[h][1] = *(const bf16x8*)(xcl + i01 + cb);
                C[h][2] = *(const bf16x8*)(xcl + i10 + cb);
                C[h][3] = *(const bf16x8*)(xcl + i11 + cb);
            }
        }
        const f32x2 W00 = {w00, w00}, W01 = {w01, w01};
        const f32x2 W10 = {w10, w10}, W11 = {w11, w11};
#pragma unroll
        for (int h = 0; h < 2; ++h) {
            const unsigned* u0 = (const unsigned*)&C[h][0];
            const unsigned* u1 = (const unsigned*)&C[h][1];
            const unsigned* u2 = (const unsigned*)&C[h][2];
            const unsigned* u3 = (const unsigned*)&C[h][3];
            unsigned avu[4];
#pragma unroll
            for (int d = 0; d < 4; ++d) {
                f32x2 s = bfpair(u0[d]) * W00;
                s = __builtin_elementwise_fma(bfpair(u1[d]), W01, s);
                s = __builtin_elementwise_fma(bfpair(u2[d]), W10, s);
                s = __builtin_elementwise_fma(bfpair(u3[d]), W11, s);
                unsigned r0 = fasu(s[0]) + 0x8000u;
                unsigned r1 = fasu(s[1]) + 0x8000u;
                avu[d] = __builtin_amdgcn_perm(r1, r0, 0x07060302u);
            }
            bf16x8 av = *(const bf16x8*)avu;
            const int kb = t * 8 + h * 4 + quad;
#pragma unroll
            for (int g = 0; g < 4; ++g) {
                bf16x8 bv = *(const bf16x8*)(wt + (kb * 64 + g * 16 + l16) * 8);
                acc[g] = __builtin_amdgcn_mfma_f32_16x16x32_bf16(av, bv, acc[g], 0, 0, 0);
            }
        }
    }
#pragma unroll
    for (int g = 0; g < 4; ++g) {
        int o = g * 16 + l16;
        float sc = gg[o] * rsqrtf(var[o] + 1e-5f);
        float off = (bias[o] - mu[o]) * sc + be[o];
#pragma unroll
        for (int r = 0; r < 4; ++r) {
            int mm = quad * 4 + r;
            int pix = base + ((ty0 + wave * 2 + (mm >> 3)) << 8) + tx0 + (mm & 7);
            float v = acc[g][r] * sc + off;
            out_cl[(size_t)pix * 64 + o] = f2bf(fmaxf(v, 0.f));
        }
    }
}

// ---------- dilated conv (dil=2 pad=2): 16x16 tile + 20x20 halo, 512 thr ----------
__global__ __launch_bounds__(512) __attribute__((amdgpu_waves_per_eu(2, 4)))
void k_conv_mfma(const short* __restrict__ in_cl,
        const short* __restrict__ wt, const float* __restrict__ bias,
        const float* __restrict__ gg, const float* __restrict__ be,
        const float* __restrict__ mu, const float* __restrict__ var,
        short* __restrict__ out_cl) {
    __shared__ short xt[400 * XPS];                  // 57.6 KB
    const int lane = threadIdx.x & 63, wave = threadIdx.x >> 6;   // wave 0..7
    const int quad = lane >> 4, l16 = lane & 15;
    const int tIdx = (blockIdx.x & 7) * 64 + (blockIdx.x >> 3);   // 512 blocks
    const int tr = tIdx >> 4, tc = tIdx & 15;
    const int b = tr >> 4;
    const int ty0 = (tr & 15) * 16, tx0 = tc * 16;
    const int base = b << 16;
    if (threadIdx.x < 400) {
        const int p = threadIdx.x;
        const int sy = ty0 - 2 + p / 20, sx = tx0 - 2 + p % 20;
        short* dst = &xt[p * XPS];
        if (((unsigned)sy < 256u) && ((unsigned)sx < 256u)) {
            const short* src = in_cl + (size_t)((base + sy * 256 + sx) * 64);
#pragma unroll
            for (int j = 0; j < 8; ++j)
                *(bf16x8*)(dst + j * 8) = *(const bf16x8*)(src + j * 8);
        } else {
            bf16x8 z = {0,0,0,0,0,0,0,0};
#pragma unroll
            for (int j = 0; j < 8; ++j) *(bf16x8*)(dst + j * 8) = z;
        }
    }
    __syncthreads();
    const int ly = wave * 2;                 // rows ly, ly+1
    f32x4 acc[2][4];
#pragma unroll
    for (int h = 0; h < 2; ++h)
#pragma unroll
        for (int g = 0; g < 4; ++g) acc[h][g] = (f32x4){0,0,0,0};

    auto loadB = [&](int s, bf16x8* Bv) {
        const int kb = s * 4 + quad;
#pragma unroll
        for (int g = 0; g < 4; ++g)
            Bv[g] = *(const bf16x8*)(wt + (kb * 64 + g * 16 + l16) * 8);
    };
    bf16x8 B[3][4];
    loadB(0, B[0]);
    loadB(1, B[1]);
#pragma unroll
    for (int s = 0; s < 18; ++s) {
        if (s + 2 < 18) loadB(s + 2, B[(s + 2) % 3]);
        const int t = s >> 1, c0 = (s & 1) * 32;
        const int dy = (t / 3 - 1) * 2, dx = (t % 3 - 1) * 2;
        const int cidx = c0 + quad * 8;
        bf16x8 a0 = *(const bf16x8*)&xt[((ly + 2 + dy) * 20 + (l16 + 2 + dx)) * XPS + cidx];
        bf16x8 a1 = *(const bf16x8*)&xt[((ly + 3 + dy) * 20 + (l16 + 2 + dx)) * XPS + cidx];
#pragma unroll
        for (int g = 0; g < 4; ++g) {
            acc[0][g] = __builtin_amdgcn_mfma_f32_16x16x32_bf16(a0, B[s % 3][g], acc[0][g], 0, 0, 0);
            acc[1][g] = __builtin_amdgcn_mfma_f32_16x16x32_bf16(a1, B[s % 3][g], acc[1][g], 0, 0, 0);
        }
    }
#pragma unroll
    for (int h = 0; h < 2; ++h)
#pragma unroll
    for (int g = 0; g < 4; ++g) {
        int o = g * 16 + l16;
        float sc = gg[o] * rsqrtf(var[o] + 1e-5f);
        float off = (bias[o] - mu[o]) * sc + be[o];
#pragma unroll
        for (int r = 0; r < 4; ++r) {
            int pix = base + ((ty0 + ly + h) << 8) + tx0 + quad * 4 + r;
            float v = acc[h][g][r] * sc + off;
            out_cl[(size_t)pix * 64 + o] = f2bf(fmaxf(v, 0.f));
        }
    }
}

// ---------- final 3x3 conv (pad=1) + sigmoid + clip : 16x16 tile + 18x18 halo ----------
__global__ __launch_bounds__(256) void k_final(const short* __restrict__ h_cl,
        const float* __restrict__ w3t, const float* __restrict__ b3,
        float* __restrict__ out) {
    __shared__ short xt[324 * XPS];                  // 46.7 KB
    const int tIdx = (blockIdx.x & 7) * 64 + (blockIdx.x >> 3);   // 512 blocks
    const int tr = tIdx >> 4, tc = tIdx & 15;
    const int b = tr >> 4;
    const int ty0 = (tr & 15) * 16, tx0 = tc * 16;
    const int base = b << 16;
    for (int p = threadIdx.x; p < 324; p += 256) {
        const int sy = ty0 - 1 + p / 18, sx = tx0 - 1 + p % 18;
        short* dst = &xt[p * XPS];
        if (((unsigned)sy < 256u) && ((unsigned)sx < 256u)) {
            const short* src = h_cl + (size_t)((base + sy * 256 + sx) * 64);
#pragma unroll
            for (int j = 0; j < 8; ++j)
                *(bf16x8*)(dst + j * 8) = *(const bf16x8*)(src + j * 8);
        } else {
            bf16x8 z = {0,0,0,0,0,0,0,0};
#pragma unroll
            for (int j = 0; j < 8; ++j) *(bf16x8*)(dst + j * 8) = z;
        }
    }
    __syncthreads();
    const int ly = threadIdx.x >> 4, lx = threadIdx.x & 15;
    float acc = 0.f;
#pragma unroll
    for (int t = 0; t < 9; ++t) {
        const int hidx = (ly + 1 + t / 3 - 1) * 18 + (lx + 1 + t % 3 - 1);
        const short* hp = &xt[hidx * XPS];
        const float* wp = w3t + t * 64;
#pragma unroll
        for (int j = 0; j < 64; j += 8) {
            bf16x8 v = *(const bf16x8*)(hp + j);
#pragma unroll
            for (int e = 0; e < 8; ++e)
                acc = fmaf(bf2f(v[e]), wp[j + e], acc);
        }
    }
    float s = 1.f / (1.f + expf(-(acc + b3[0])));
    out[base + ((ty0 + ly) << 8) + tx0 + lx] = fminf(fmaxf(s, 1e-4f), 1.f - 1e-4f);
}

extern "C" void kernel_launch(void* const* d_in, const int* in_sizes, int n_in,
                              void* d_out, int out_size, void* d_ws, size_t ws_size,
                              hipStream_t stream) {
    const float* x     = (const float*)d_in[0];
    const float* w_om  = (const float*)d_in[1];
    const float* b_om  = (const float*)d_in[2];
    const float* w_dcn = (const float*)d_in[3];
    const float* b_dcn = (const float*)d_in[4];
    const float* bn1g = (const float*)d_in[5],  *bn1b = (const float*)d_in[6];
    const float* bn1m = (const float*)d_in[7],  *bn1v = (const float*)d_in[8];
    const float* bn2g = (const float*)d_in[9],  *bn2b = (const float*)d_in[10];
    const float* bn2m = (const float*)d_in[11], *bn2v = (const float*)d_in[12];
    const float* bn3g = (const float*)d_in[13], *bn3b = (const float*)d_in[14];
    const float* bn3m = (const float*)d_in[15], *bn3v = (const float*)d_in[16];
    const float* w_h = (const float*)d_in[17], *b_h = (const float*)d_in[18];
    const float* w_w = (const float*)d_in[19], *b_w = (const float*)d_in[20];
    const float* w3  = (const float*)d_in[21], *b3  = (const float*)d_in[22];
    float* outp = (float*)d_out;

    // workspace layout
    char* ws = (char*)d_ws;
    short* xcl   = (short*)ws;                         // bf16 16.78 MB
    short* h1    = xcl + (size_t)NPX * 64;
    short* h2    = h1 + (size_t)NPX * 64;
    short* wt_om  = h2 + (size_t)NPX * 64;             // 32*576 bf16
    short* wt_dcn = wt_om  + 32 * 576;                 // 64*576 bf16
    short* wt_h   = wt_dcn + 64 * 576;
    short* wt_w   = wt_h   + 64 * 576;
    float* w3t    = (float*)(wt_w + 64 * 576);         // 576 fp32

    dim3 blk(256);
    k_x2cl<<<512, blk, 0, stream>>>(x, xcl, w_om, w_dcn, w_h, w_w, w3,
                                    wt_om, wt_dcn, wt_h, wt_w, w3t);
    k_dcn_mfma<<<1024, blk, 0, stream>>>(xcl, wt_om, b_om, wt_dcn, b_dcn,
                                         bn1g, bn1b, bn1m, bn1v, h1, 0);
    k_dcn_mfma<<<1024, blk, 0, stream>>>(xcl, wt_om, b_om, wt_dcn, b_dcn,
                                         bn1g, bn1b, bn1m, bn1v, h1, 1024);
    k_conv_mfma<<<512, dim3(512), 0, stream>>>(h1, wt_h, b_h, bn2g, bn2b, bn2m, bn2v, h2);
    k_conv_mfma<<<512, dim3(512), 0, stream>>>(h2, wt_w, b_w, bn3g, bn3b, bn3m, bn3v, h1);
    k_final<<<512, blk, 0, stream>>>(h1, w3t, b3, outp);
}

// Round 21
// 217.998 us; speedup vs baseline: 1.0326x; 1.0326x over previous
//
#include <hip/hip_runtime.h>
#include <math.h>

#define HH 256
#define WW 256
#define HW (HH*WW)
#define NPX (2*HW)          // 131072 pixels total

typedef __attribute__((ext_vector_type(8))) short bf16x8;
typedef __attribute__((ext_vector_type(4))) float f32x4;
typedef __attribute__((ext_vector_type(2))) float f32x2;

__device__ __forceinline__ float bf2f(short h) {
    union { unsigned u; float f; } v; v.u = ((unsigned)(unsigned short)h) << 16; return v.f;
}
__device__ __forceinline__ short f2bf(float f) {        // RNE
    union { float f; unsigned u; } v; v.f = f;
    unsigned r = v.u + 0x7fffu + ((v.u >> 16) & 1u);
    return (short)(r >> 16);
}
__device__ __forceinline__ float uasf(unsigned u) {
    union { unsigned u; float f; } v; v.u = u; return v.f;
}
__device__ __forceinline__ unsigned fasu(float f) {
    union { float f; unsigned u; } v; v.f = f; return v.u;
}
// unpack dword holding 2 bf16 (lo=elem0, hi=elem1) -> f32x2
__device__ __forceinline__ f32x2 bfpair(unsigned u) {
    f32x2 r; r[0] = uasf(u << 16); r[1] = uasf(u & 0xffff0000u); return r;
}

// ---------- x NCHW fp32 -> channel-last bf16 + (blocks 0..143) weight prep ----------
// wt3 layout: [kb=k/8][n][j=k%8]  (k = t*64+c)
__global__ __launch_bounds__(256) void k_x2cl(const float* __restrict__ x,
        short* __restrict__ xcl,
        const float* __restrict__ w_om, const float* __restrict__ w_dcn,
        const float* __restrict__ w_h,  const float* __restrict__ w_w,
        const float* __restrict__ w3,
        short* __restrict__ wt_om, short* __restrict__ wt_dcn,
        short* __restrict__ wt_h,  short* __restrict__ wt_w,
        float* __restrict__ w3t) {
    __shared__ short tile[256 * 66];
    const int xx = threadIdx.x;
    const int row = blockIdx.x;               // b*256 + y
    const int b = row >> 8, y = row & 255;
    for (int c = 0; c < 64; ++c)
        tile[xx * 66 + c] = f2bf(x[((b * 64 + c) << 16) + (y << 8) + xx]);
    int i = blockIdx.x * 256 + threadIdx.x;
    if (i < 64 * 576) {
        int o = i / 576, k = i - o * 576, t = k >> 6, c = k & 63;
        int kb = k >> 3, j = k & 7;
        int src = (o * 64 + c) * 9 + t;
        int dst = (kb * 64 + o) * 8 + j;
        wt_dcn[dst] = f2bf(w_dcn[src]);
        wt_h[dst]   = f2bf(w_h[src]);
        wt_w[dst]   = f2bf(w_w[src]);
        if (o < 32) wt_om[(kb * 32 + o) * 8 + j] = (o < 27) ? f2bf(w_om[src]) : (short)0;
        if (o == 0) w3t[k] = w3[c * 9 + t];
    }
    __syncthreads();
    short* op = xcl + ((row << 8) + xx) * 64;
#pragma unroll
    for (int j = 0; j < 8; ++j) {
        bf16x8 v;
#pragma unroll
        for (int e = 0; e < 8; ++e) v[e] = tile[xx * 66 + j * 8 + e];
        *(bf16x8*)(op + j * 8) = v;
    }
}

#define XPS 72   // LDS pixel stride (shorts): 144B, 16B-aligned

// ---------- FUSED om-conv + modulated deformable conv + BN1 + ReLU ----------
// om_lds stored fp16 -> total LDS 40,448B => 4 blocks/CU, no grid tail.
__global__ __launch_bounds__(256) __attribute__((amdgpu_waves_per_eu(2, 4)))
void k_dcn_mfma(const short* __restrict__ xcl,
        const short* __restrict__ wom, const float* __restrict__ b_om,
        const short* __restrict__ wt,
        const float* __restrict__ bias,
        const float* __restrict__ gg, const float* __restrict__ be,
        const float* __restrict__ mu, const float* __restrict__ var,
        short* __restrict__ out_cl) {
    __shared__ short xt[256 * XPS];                 // 36,864 B
    __shared__ _Float16 om_lds[64 * 28];            //  3,584 B
    const int lane = threadIdx.x & 63, wave = threadIdx.x >> 6;
    const int quad = lane >> 4, l16 = lane & 15;
    const int band = blockIdx.x & 7, idx = blockIdx.x >> 3;
    const int tr = band * 8 + (idx >> 5), tc = idx & 31;
    const int b = tr >> 5;
    const int ty0 = (tr & 31) * 8, tx0 = tc * 8;
    const int base = b << 16;
    const int hy0 = ty0 - 4, hx0 = tx0 - 4;
    // ---- stage 16x16 halo (clamped) ----
    {
        const int p = threadIdx.x;
        const int sy = min(max(hy0 + (p >> 4), 0), 255);
        const int sx = min(max(hx0 + (p & 15), 0), 255);
        const short* src = xcl + (size_t)((base + sy * 256 + sx) * 64);
        short* dst = &xt[p * XPS];
#pragma unroll
        for (int j = 0; j < 8; ++j)
            *(bf16x8*)(dst + j * 8) = *(const bf16x8*)(src + j * 8);
    }
    __syncthreads();

    const int lp = wave * 16 + l16;        // tile-local pixel (A-row m=l16)
    const int pyy = lp >> 3, pxx = lp & 7;
    const int y = ty0 + pyy, x = tx0 + pxx;

    // ---- phase 1: om conv for this tile (zero-OOB taps) ----
    {
        f32x4 oacc[2];
        oacc[0] = (f32x4){0,0,0,0}; oacc[1] = (f32x4){0,0,0,0};
        auto loadOB = [&](int s, bf16x8* Bv) {
            const int kb = s * 4 + quad;
#pragma unroll
            for (int g = 0; g < 2; ++g)
                Bv[g] = *(const bf16x8*)(wom + (kb * 32 + g * 16 + l16) * 8);
        };
        bf16x8 OB[2][2];
        loadOB(0, OB[0]);
#pragma unroll
        for (int s = 0; s < 18; ++s) {
            if (s < 17) loadOB(s + 1, OB[(s + 1) & 1]);
            const int t = s >> 1, c0 = (s & 1) * 32;
            const int dy = t / 3 - 1, dx = t % 3 - 1;
            bf16x8 av = *(const bf16x8*)&xt[((pyy + 4 + dy) * 16 + (pxx + 4 + dx)) * XPS + c0 + quad * 8];
            bool ok = ((unsigned)(y + dy) < 256u) && ((unsigned)(x + dx) < 256u);
            if (!ok) { bf16x8 z = {0,0,0,0,0,0,0,0}; av = z; }
#pragma unroll
            for (int g = 0; g < 2; ++g)
                oacc[g] = __builtin_amdgcn_mfma_f32_16x16x32_bf16(av, OB[s & 1][g], oacc[g], 0, 0, 0);
        }
#pragma unroll
        for (int g = 0; g < 2; ++g) {
            int o = g * 16 + l16;
            if (o < 27) {
                float bo = b_om[o];
#pragma unroll
                for (int r = 0; r < 4; ++r) {
                    float v = oacc[g][r] + bo;
                    if (o >= 18) v = 1.f / (1.f + expf(-v));     // sigmoid(mask)
                    om_lds[(wave * 16 + quad * 4 + r) * 28 + o] = (_Float16)v;
                }
            }
        }
    }
    __syncthreads();

    // ---- phase 2: deformable conv ----
    f32x4 acc[4];
#pragma unroll
    for (int i = 0; i < 4; ++i) acc[i] = (f32x4){0,0,0,0};

    float omr[27];
#pragma unroll
    for (int j = 0; j < 27; ++j) omr[j] = (float)om_lds[lp * 28 + j];

#pragma unroll
    for (int t = 0; t < 9; ++t) {
        const int ky = t / 3 - 1, kx = t % 3 - 1;
        float o1 = omr[t], o2 = omr[9 + t], m = omr[18 + t];
        float py = (float)(y + ky) + o1;
        float px = (float)(x + kx) + o2;
        float y0f = floorf(py), x0f = floorf(px);
        float wy1 = py - y0f, wx1 = px - x0f;
        int y0 = (int)y0f, xi0 = (int)x0f, y1 = y0 + 1, xi1 = xi0 + 1;
        float w00 = (1.f - wy1) * (1.f - wx1) * m;
        float w01 = (1.f - wy1) * wx1 * m;
        float w10 = wy1 * (1.f - wx1) * m;
        float w11 = wy1 * wx1 * m;
        if (!((unsigned)y0  < 256u)) { w00 = 0.f; w01 = 0.f; }
        if (!((unsigned)y1  < 256u)) { w10 = 0.f; w11 = 0.f; }
        if (!((unsigned)xi0 < 256u)) { w00 = 0.f; w10 = 0.f; }
        if (!((unsigned)xi1 < 256u)) { w01 = 0.f; w11 = 0.f; }
        int cy0 = min(max(y0, 0), 255), cy1 = min(max(y1, 0), 255);
        int cx0 = min(max(xi0, 0), 255), cx1 = min(max(xi1, 0), 255);
        int iy0 = cy0 - hy0, iy1 = cy1 - hy0;
        int ix0 = cx0 - hx0, ix1 = cx1 - hx0;
        bool inh = ((unsigned)iy0 < 16u) && ((unsigned)iy1 < 16u)
                && ((unsigned)ix0 < 16u) && ((unsigned)ix1 < 16u);

        bf16x8 C[2][4];
        if (__all(inh)) {
            const int p00 = (iy0 * 16 + ix0) * XPS, p01 = (iy0 * 16 + ix1) * XPS;
            const int p10 = (iy1 * 16 + ix0) * XPS, p11 = (iy1 * 16 + ix1) * XPS;
#pragma unroll
            for (int h = 0; h < 2; ++h) {
                const int cb = h * 32 + quad * 8;
                C[h][0] = *(const bf16x8*)&xt[p00 + cb];
                C[h][1] = *(const bf16x8*)&xt[p01 + cb];
                C[h][2] = *(const bf16x8*)&xt[p10 + cb];
                C[h][3] = *(const bf16x8*)&xt[p11 + cb];
            }
        } else {
            const int i00 = (base + cy0 * 256 + cx0) * 64;
            const int i01 = (base + cy0 * 256 + cx1) * 64;
            const int i10 = (base + cy1 * 256 + cx0) * 64;
            const int i11 = (base + cy1 * 256 + cx1) * 64;
#pragma unroll
            for (int h = 0; h < 2; ++h) {
                const int cb = h * 32 + quad * 8;
                C[h][0] = *(const bf16x8*)(xcl + i00 + cb);
                C[h][1] = *(const bf16x8*)(xcl + i01 + cb);
                C[h][2] = *(const bf16x8*)(xcl + i10 + cb);
                C[h][3] = *(const bf16x8*)(xcl + i11 + cb);
            }
        }
        const f32x2 W00 = {w00, w00}, W01 = {w01, w01};
        const f32x2 W10 = {w10, w10}, W11 = {w11, w11};
#pragma unroll
        for (int h = 0; h < 2; ++h) {
            const unsigned* u0 = (const unsigned*)&C[h][0];
            const unsigned* u1 = (const unsigned*)&C[h][1];
            const unsigned* u2 = (const unsigned*)&C[h][2];
            const unsigned* u3 = (const unsigned*)&C[h][3];
            unsigned avu[4];
#pragma unroll
            for (int d = 0; d < 4; ++d) {
                f32x2 s = bfpair(u0[d]) * W00;
                s = __builtin_elementwise_fma(bfpair(u1[d]), W01, s);
                s = __builtin_elementwise_fma(bfpair(u2[d]), W10, s);
                s = __builtin_elementwise_fma(bfpair(u3[d]), W11, s);
                unsigned r0 = fasu(s[0]) + 0x8000u;
                unsigned r1 = fasu(s[1]) + 0x8000u;
                avu[d] = __builtin_amdgcn_perm(r1, r0, 0x07060302u);
            }
            bf16x8 av = *(const bf16x8*)avu;
            const int kb = t * 8 + h * 4 + quad;
#pragma unroll
            for (int g = 0; g < 4; ++g) {
                bf16x8 bv = *(const bf16x8*)(wt + (kb * 64 + g * 16 + l16) * 8);
                acc[g] = __builtin_amdgcn_mfma_f32_16x16x32_bf16(av, bv, acc[g], 0, 0, 0);
            }
        }
    }
#pragma unroll
    for (int g = 0; g < 4; ++g) {
        int o = g * 16 + l16;
        float sc = gg[o] * rsqrtf(var[o] + 1e-5f);
        float off = (bias[o] - mu[o]) * sc + be[o];
#pragma unroll
        for (int r = 0; r < 4; ++r) {
            int mm = quad * 4 + r;
            int pix = base + ((ty0 + wave * 2 + (mm >> 3)) << 8) + tx0 + (mm & 7);
            float v = acc[g][r] * sc + off;
            out_cl[(size_t)pix * 64 + o] = f2bf(fmaxf(v, 0.f));
        }
    }
}

// ---------- dilated conv (dil=2 pad=2): 16x16 tile + 20x20 halo, 512 thr ----------
__global__ __launch_bounds__(512) __attribute__((amdgpu_waves_per_eu(2, 4)))
void k_conv_mfma(const short* __restrict__ in_cl,
        const short* __restrict__ wt, const float* __restrict__ bias,
        const float* __restrict__ gg, const float* __restrict__ be,
        const float* __restrict__ mu, const float* __restrict__ var,
        short* __restrict__ out_cl) {
    __shared__ short xt[400 * XPS];                  // 57.6 KB
    const int lane = threadIdx.x & 63, wave = threadIdx.x >> 6;   // wave 0..7
    const int quad = lane >> 4, l16 = lane & 15;
    const int tIdx = (blockIdx.x & 7) * 64 + (blockIdx.x >> 3);   // 512 blocks
    const int tr = tIdx >> 4, tc = tIdx & 15;
    const int b = tr >> 4;
    const int ty0 = (tr & 15) * 16, tx0 = tc * 16;
    const int base = b << 16;
    if (threadIdx.x < 400) {
        const int p = threadIdx.x;
        const int sy = ty0 - 2 + p / 20, sx = tx0 - 2 + p % 20;
        short* dst = &xt[p * XPS];
        if (((unsigned)sy < 256u) && ((unsigned)sx < 256u)) {
            const short* src = in_cl + (size_t)((base + sy * 256 + sx) * 64);
#pragma unroll
            for (int j = 0; j < 8; ++j)
                *(bf16x8*)(dst + j * 8) = *(const bf16x8*)(src + j * 8);
        } else {
            bf16x8 z = {0,0,0,0,0,0,0,0};
#pragma unroll
            for (int j = 0; j < 8; ++j) *(bf16x8*)(dst + j * 8) = z;
        }
    }
    __syncthreads();
    const int ly = wave * 2;                 // rows ly, ly+1
    f32x4 acc[2][4];
#pragma unroll
    for (int h = 0; h < 2; ++h)
#pragma unroll
        for (int g = 0; g < 4; ++g) acc[h][g] = (f32x4){0,0,0,0};

    auto loadB = [&](int s, bf16x8* Bv) {
        const int kb = s * 4 + quad;
#pragma unroll
        for (int g = 0; g < 4; ++g)
            Bv[g] = *(const bf16x8*)(wt + (kb * 64 + g * 16 + l16) * 8);
    };
    bf16x8 B[3][4];
    loadB(0, B[0]);
    loadB(1, B[1]);
#pragma unroll
    for (int s = 0; s < 18; ++s) {
        if (s + 2 < 18) loadB(s + 2, B[(s + 2) % 3]);
        const int t = s >> 1, c0 = (s & 1) * 32;
        const int dy = (t / 3 - 1) * 2, dx = (t % 3 - 1) * 2;
        const int cidx = c0 + quad * 8;
        bf16x8 a0 = *(const bf16x8*)&xt[((ly + 2 + dy) * 20 + (l16 + 2 + dx)) * XPS + cidx];
        bf16x8 a1 = *(const bf16x8*)&xt[((ly + 3 + dy) * 20 + (l16 + 2 + dx)) * XPS + cidx];
#pragma unroll
        for (int g = 0; g < 4; ++g) {
            acc[0][g] = __builtin_amdgcn_mfma_f32_16x16x32_bf16(a0, B[s % 3][g], acc[0][g], 0, 0, 0);
            acc[1][g] = __builtin_amdgcn_mfma_f32_16x16x32_bf16(a1, B[s % 3][g], acc[1][g], 0, 0, 0);
        }
    }
#pragma unroll
    for (int h = 0; h < 2; ++h)
#pragma unroll
    for (int g = 0; g < 4; ++g) {
        int o = g * 16 + l16;
        float sc = gg[o] * rsqrtf(var[o] + 1e-5f);
        float off = (bias[o] - mu[o]) * sc + be[o];
#pragma unroll
        for (int r = 0; r < 4; ++r) {
            int pix = base + ((ty0 + ly + h) << 8) + tx0 + quad * 4 + r;
            float v = acc[h][g][r] * sc + off;
            out_cl[(size_t)pix * 64 + o] = f2bf(fmaxf(v, 0.f));
        }
    }
}

// ---------- final 3x3 conv (pad=1) + sigmoid + clip : 16x16 tile + 18x18 halo ----------
__global__ __launch_bounds__(256) void k_final(const short* __restrict__ h_cl,
        const float* __restrict__ w3t, const float* __restrict__ b3,
        float* __restrict__ out) {
    __shared__ short xt[324 * XPS];                  // 46.7 KB
    const int tIdx = (blockIdx.x & 7) * 64 + (blockIdx.x >> 3);   // 512 blocks
    const int tr = tIdx >> 4, tc = tIdx & 15;
    const int b = tr >> 4;
    const int ty0 = (tr & 15) * 16, tx0 = tc * 16;
    const int base = b << 16;
    for (int p = threadIdx.x; p < 324; p += 256) {
        const int sy = ty0 - 1 + p / 18, sx = tx0 - 1 + p % 18;
        short* dst = &xt[p * XPS];
        if (((unsigned)sy < 256u) && ((unsigned)sx < 256u)) {
            const short* src = h_cl + (size_t)((base + sy * 256 + sx) * 64);
#pragma unroll
            for (int j = 0; j < 8; ++j)
                *(bf16x8*)(dst + j * 8) = *(const bf16x8*)(src + j * 8);
        } else {
            bf16x8 z = {0,0,0,0,0,0,0,0};
#pragma unroll
            for (int j = 0; j < 8; ++j) *(bf16x8*)(dst + j * 8) = z;
        }
    }
    __syncthreads();
    const int ly = threadIdx.x >> 4, lx = threadIdx.x & 15;
    float acc = 0.f;
#pragma unroll
    for (int t = 0; t < 9; ++t) {
        const int hidx = (ly + 1 + t / 3 - 1) * 18 + (lx + 1 + t % 3 - 1);
        const short* hp = &xt[hidx * XPS];
        const float* wp = w3t + t * 64;
#pragma unroll
        for (int j = 0; j < 64; j += 8) {
            bf16x8 v = *(const bf16x8*)(hp + j);
#pragma unroll
            for (int e = 0; e < 8; ++e)
                acc = fmaf(bf2f(v[e]), wp[j + e], acc);
        }
    }
    float s = 1.f / (1.f + expf(-(acc + b3[0])));
    out[base + ((ty0 + ly) << 8) + tx0 + lx] = fminf(fmaxf(s, 1e-4f), 1.f - 1e-4f);
}

extern "C" void kernel_launch(void* const* d_in, const int* in_sizes, int n_in,
                              void* d_out, int out_size, void* d_ws, size_t ws_size,
                              hipStream_t stream) {
    const float* x     = (const float*)d_in[0];
    const float* w_om  = (const float*)d_in[1];
    const float* b_om  = (const float*)d_in[2];
    const float* w_dcn = (const float*)d_in[3];
    const float* b_dcn = (const float*)d_in[4];
    const float* bn1g = (const float*)d_in[5],  *bn1b = (const float*)d_in[6];
    const float* bn1m = (const float*)d_in[7],  *bn1v = (const float*)d_in[8];
    const float* bn2g = (const float*)d_in[9],  *bn2b = (const float*)d_in[10];
    const float* bn2m = (const float*)d_in[11], *bn2v = (const float*)d_in[12];
    const float* bn3g = (const float*)d_in[13], *bn3b = (const float*)d_in[14];
    const float* bn3m = (const float*)d_in[15], *bn3v = (const float*)d_in[16];
    const float* w_h = (const float*)d_in[17], *b_h = (const float*)d_in[18];
    const float* w_w = (const float*)d_in[19], *b_w = (const float*)d_in[20];
    const float* w3  = (const float*)d_in[21], *b3  = (const float*)d_in[22];
    float* outp = (float*)d_out;

    // workspace layout
    char* ws = (char*)d_ws;
    short* xcl   = (short*)ws;                         // bf16 16.78 MB
    short* h1    = xcl + (size_t)NPX * 64;
    short* h2    = h1 + (size_t)NPX * 64;
    short* wt_om  = h2 + (size_t)NPX * 64;             // 32*576 bf16
    short* wt_dcn = wt_om  + 32 * 576;                 // 64*576 bf16
    short* wt_h   = wt_dcn + 64 * 576;
    short* wt_w   = wt_h   + 64 * 576;
    float* w3t    = (float*)(wt_w + 64 * 576);         // 576 fp32

    dim3 blk(256);
    k_x2cl<<<512, blk, 0, stream>>>(x, xcl, w_om, w_dcn, w_h, w_w, w3,
                                    wt_om, wt_dcn, wt_h, wt_w, w3t);
    k_dcn_mfma<<<NPX / 64, blk, 0, stream>>>(xcl, wt_om, b_om, wt_dcn, b_dcn,
                                             bn1g, bn1b, bn1m, bn1v, h1);
    k_conv_mfma<<<512, dim3(512), 0, stream>>>(h1, wt_h, b_h, bn2g, bn2b, bn2m, bn2v, h2);
    k_conv_mfma<<<512, dim3(512), 0, stream>>>(h2, wt_w, b_w, bn3g, bn3b, bn3m, bn3v, h1);
    k_final<<<512, blk, 0, stream>>>(h1, w3t, b3, outp);
}